// Round 1
// baseline (623.628 us; speedup 1.0000x reference)
//
#include <hip/hip_runtime.h>
#include <hip/hip_bf16.h>

#define N_   8192
#define DIM_ 512
#define DK_  128
#define DV_  512

typedef short short8 __attribute__((ext_vector_type(8)));
typedef float f32x4  __attribute__((ext_vector_type(4)));

__device__ __forceinline__ ushort f2bf(float f) {
    union { float f; unsigned u; } v; v.f = f;
    unsigned u = v.u;
    return (ushort)((u + 0x7FFFu + ((u >> 16) & 1u)) >> 16);
}

// ---- kernel 1: u1 = w_w^T a1, u2 = w_w^T a2, c1 = w_b.a1, c2 = w_b.a2 ----
__global__ void prep_kernel(const float* __restrict__ w_w, const float* __restrict__ w_b,
                            const float* __restrict__ a, float* __restrict__ u1,
                            float* __restrict__ u2, float* __restrict__ scal) {
    int d = threadIdx.x;                 // 512 threads
    float s1 = 0.f, s2 = 0.f;
    for (int k = 0; k < DK_; ++k) {
        float w = w_w[k * DIM_ + d];
        s1 += w * a[k];
        s2 += w * a[DK_ + k];
    }
    u1[d] = s1; u2[d] = s2;
    if (d == 0) { float c = 0.f; for (int k = 0; k < DK_; ++k) c += w_b[k] * a[k];        scal[0] = c; }
    if (d == 1) { float c = 0.f; for (int k = 0; k < DK_; ++k) c += w_b[k] * a[DK_ + k];  scal[1] = c; }
}

// ---- kernel 2: e_src[i] = x[i].u1 + c1 ; e_dst[i] = x[i].u2 + c2 (1 wave/row) ----
__global__ __launch_bounds__(256) void e_kernel(const float* __restrict__ x,
        const float* __restrict__ u1, const float* __restrict__ u2,
        const float* __restrict__ scal, float* __restrict__ e_src, float* __restrict__ e_dst) {
    int wid = threadIdx.x >> 6, lane = threadIdx.x & 63;
    int row = blockIdx.x * 4 + wid;
    const float* xr = x + (size_t)row * DIM_;
    int d0 = lane * 8;
    f32x4 xa = *(const f32x4*)(xr + d0);
    f32x4 xb = *(const f32x4*)(xr + d0 + 4);
    f32x4 ua = *(const f32x4*)(u1 + d0);
    f32x4 ub = *(const f32x4*)(u1 + d0 + 4);
    f32x4 va = *(const f32x4*)(u2 + d0);
    f32x4 vb = *(const f32x4*)(u2 + d0 + 4);
    float s1 = 0.f, s2 = 0.f;
    for (int e = 0; e < 4; ++e) {
        s1 += xa[e] * ua[e] + xb[e] * ub[e];
        s2 += xa[e] * va[e] + xb[e] * vb[e];
    }
    for (int off = 32; off; off >>= 1) { s1 += __shfl_xor(s1, off); s2 += __shfl_xor(s2, off); }
    if (lane == 0) { e_src[row] = s1 + scal[0]; e_dst[row] = s2 + scal[1]; }
}

// ---- kernel 3: M = max_j e_dst[j] ----
__global__ void max_kernel(const float* __restrict__ e_dst, float* __restrict__ scal) {
    __shared__ float red[256];
    int t = threadIdx.x;
    float m = -1e30f;
    for (int i = t; i < N_; i += 256) m = fmaxf(m, e_dst[i]);
    red[t] = m; __syncthreads();
    for (int s = 128; s; s >>= 1) { if (t < s) red[t] = fmaxf(red[t], red[t + s]); __syncthreads(); }
    if (t == 0) scal[2] = red[0];
}

// ---- kernel 4: vT[c][j] = bf16( x[j]. wv_w[c] + wv_b[c] ), MFMA, on-the-fly bf16 cast ----
__global__ __launch_bounds__(256) void vt_kernel(const float* __restrict__ x,
        const float* __restrict__ wv_w, const float* __restrict__ wv_b,
        ushort* __restrict__ vT) {
    int wid = threadIdx.x >> 6, lane = threadIdx.x & 63;
    int ln16 = lane & 15, kg = lane >> 4;
    int cb = blockIdx.y * 64;                 // c block (8 blocks)
    int jb = blockIdx.x * 256 + wid * 64;     // j block (32 blocks x 4 waves)
    f32x4 acc[4][4] = {};
    for (int k0 = 0; k0 < DIM_; k0 += 32) {
        int kk = k0 + kg * 8;
        short8 afr[4], bfr[4];
        for (int mg = 0; mg < 4; ++mg) {
            const float* p = wv_w + (size_t)(cb + mg * 16 + ln16) * DIM_ + kk;
            f32x4 lo = *(const f32x4*)p, hi = *(const f32x4*)(p + 4);
            short8 f;
            for (int e = 0; e < 4; ++e) { f[e] = (short)f2bf(lo[e]); f[e + 4] = (short)f2bf(hi[e]); }
            afr[mg] = f;
        }
        for (int ng = 0; ng < 4; ++ng) {
            const float* p = x + (size_t)(jb + ng * 16 + ln16) * DIM_ + kk;
            f32x4 lo = *(const f32x4*)p, hi = *(const f32x4*)(p + 4);
            short8 f;
            for (int e = 0; e < 4; ++e) { f[e] = (short)f2bf(lo[e]); f[e + 4] = (short)f2bf(hi[e]); }
            bfr[ng] = f;
        }
        for (int mg = 0; mg < 4; ++mg)
            for (int ng = 0; ng < 4; ++ng)
                acc[mg][ng] = __builtin_amdgcn_mfma_f32_16x16x32_bf16(afr[mg], bfr[ng], acc[mg][ng], 0, 0, 0);
    }
    for (int mg = 0; mg < 4; ++mg) {
        for (int r = 0; r < 4; ++r) {
            int c_row = cb + mg * 16 + kg * 4 + r;
            float bias = wv_b[c_row];
            for (int ng = 0; ng < 4; ++ng) {
                int j_col = jb + ng * 16 + ln16;
                vT[(size_t)c_row * N_ + j_col] = f2bf(acc[mg][ng][r] + bias);
            }
        }
    }
}

// ---- kernel 5: out = softmax(leaky(e_src_i + e_dst_j)) @ V, P generated in registers ----
__global__ __launch_bounds__(256) void attn_kernel(const ushort* __restrict__ vT,
        const float* __restrict__ e_src, const float* __restrict__ e_dst,
        const float* __restrict__ scal, float* __restrict__ out) {
    int wid = threadIdx.x >> 6, lane = threadIdx.x & 63;
    int ln16 = lane & 15, kg = lane >> 4;
    int ib = blockIdx.x * 64 + wid * 16;   // 16 output rows per wave
    int cb = blockIdx.y * 128;             // 128 output cols per block
    float M = scal[2];
    float es = e_src[ib + ln16];
    float sm = es + M;
    float m = fmaxf(sm, 0.01f * sm);       // analytic row max of leaky_relu logits

    f32x4 acc[8] = {};
    f32x4 zacc = {};
    short8 ones;
    for (int e = 0; e < 8; ++e) ones[e] = (short)0x3F80;  // bf16 1.0

    const ushort* vbase[8];
    for (int ng = 0; ng < 8; ++ng) vbase[ng] = vT + (size_t)(cb + ng * 16 + ln16) * N_;

    for (int jb = 0; jb < N_; jb += 32) {
        int jj = jb + kg * 8;
        f32x4 ed0 = *(const f32x4*)(e_dst + jj);
        f32x4 ed1 = *(const f32x4*)(e_dst + jj + 4);
        short8 pa;
        for (int e = 0; e < 4; ++e) {
            float s = es + ed0[e]; s = fmaxf(s, 0.01f * s);
            pa[e] = (short)f2bf(__expf(s - m));
            float s2 = es + ed1[e]; s2 = fmaxf(s2, 0.01f * s2);
            pa[e + 4] = (short)f2bf(__expf(s2 - m));
        }
        for (int ng = 0; ng < 8; ++ng) {
            short8 b = *(const short8*)(vbase[ng] + jj);
            acc[ng] = __builtin_amdgcn_mfma_f32_16x16x32_bf16(pa, b, acc[ng], 0, 0, 0);
        }
        zacc = __builtin_amdgcn_mfma_f32_16x16x32_bf16(pa, ones, zacc, 0, 0, 0);  // Z row-sums, free layout match
    }

    for (int r = 0; r < 4; ++r) {
        int row = ib + kg * 4 + r;
        float rz = 1.0f / zacc[r];
        for (int ng = 0; ng < 8; ++ng)
            out[(size_t)row * DV_ + cb + ng * 16 + ln16] = acc[ng][r] * rz;
    }
}

extern "C" void kernel_launch(void* const* d_in, const int* in_sizes, int n_in,
                              void* d_out, int out_size, void* d_ws, size_t ws_size,
                              hipStream_t stream) {
    const float* x    = (const float*)d_in[0];
    const float* w_w  = (const float*)d_in[1];
    const float* w_b  = (const float*)d_in[2];
    const float* wv_w = (const float*)d_in[3];
    const float* wv_b = (const float*)d_in[4];
    const float* a    = (const float*)d_in[5];
    float* out = (float*)d_out;
    char* ws = (char*)d_ws;

    ushort* vT    = (ushort*)ws;                    // 512*8192*2 = 8,388,608 B
    float*  u1    = (float*)(ws + 8388608);         // 2 KiB
    float*  u2    = (float*)(ws + 8390656);         // 2 KiB
    float*  e_src = (float*)(ws + 8392704);         // 32 KiB
    float*  e_dst = (float*)(ws + 8425472);         // 32 KiB
    float*  scal  = (float*)(ws + 8458240);         // c1, c2, M

    hipLaunchKernelGGL(prep_kernel, dim3(1),        dim3(512), 0, stream, w_w, w_b, a, u1, u2, scal);
    hipLaunchKernelGGL(e_kernel,    dim3(N_ / 4),   dim3(256), 0, stream, x, u1, u2, scal, e_src, e_dst);
    hipLaunchKernelGGL(max_kernel,  dim3(1),        dim3(256), 0, stream, e_dst, scal);
    hipLaunchKernelGGL(vt_kernel,   dim3(32, 8),    dim3(256), 0, stream, x, wv_w, wv_b, vT);
    hipLaunchKernelGGL(attn_kernel, dim3(128, 4),   dim3(256), 0, stream, vT, e_src, e_dst, scal, out);
}

// Round 3
// 200.619 us; speedup vs baseline: 3.1085x; 3.1085x over previous
//
#include <hip/hip_runtime.h>
#include <hip/hip_bf16.h>

#define N_   8192
#define DIM_ 512
#define DK_  128
#define DV_  512
#define L2E_  1.44269504088896f
#define CBIAS_ 0.0028169f   // +half-ulp trunc compensation in exp2 domain

typedef short short8 __attribute__((ext_vector_type(8)));
typedef float f32x4  __attribute__((ext_vector_type(4)));

__device__ __forceinline__ float fexp2(float x) { return __builtin_amdgcn_exp2f(x); }

__device__ __forceinline__ ushort f2bf(float f) {
    union { float f; unsigned u; } v; v.f = f;
    unsigned u = v.u;
    return (ushort)((u + 0x7FFFu + ((u >> 16) & 1u)) >> 16);
}

// ---- kernel 1: u1 = w_w^T a1, u2 = w_w^T a2, c1 = w_b.a1, c2 = w_b.a2 ----
__global__ void prep_kernel(const float* __restrict__ w_w, const float* __restrict__ w_b,
                            const float* __restrict__ a, float* __restrict__ u1,
                            float* __restrict__ u2, float* __restrict__ scal) {
    int d = threadIdx.x;                 // 512 threads
    float s1 = 0.f, s2 = 0.f;
    for (int k = 0; k < DK_; ++k) {
        float w = w_w[k * DIM_ + d];
        s1 += w * a[k];
        s2 += w * a[DK_ + k];
    }
    u1[d] = s1; u2[d] = s2;
    if (d == 0) { float c = 0.f; for (int k = 0; k < DK_; ++k) c += w_b[k] * a[k];        scal[0] = c; }
    if (d == 1) { float c = 0.f; for (int k = 0; k < DK_; ++k) c += w_b[k] * a[DK_ + k];  scal[1] = c; }
}

// ---- kernel 2: e_src[i], e_dst[i], plus exp2-prescaled copies of e_dst ----
__global__ __launch_bounds__(256) void e_kernel(const float* __restrict__ x,
        const float* __restrict__ u1, const float* __restrict__ u2,
        const float* __restrict__ scal, float* __restrict__ e_src, float* __restrict__ e_dst,
        float* __restrict__ edl, float* __restrict__ edl01) {
    int wid = threadIdx.x >> 6, lane = threadIdx.x & 63;
    int row = blockIdx.x * 4 + wid;
    const float* xr = x + (size_t)row * DIM_;
    int d0 = lane * 8;
    f32x4 xa = *(const f32x4*)(xr + d0);
    f32x4 xb = *(const f32x4*)(xr + d0 + 4);
    f32x4 ua = *(const f32x4*)(u1 + d0);
    f32x4 ub = *(const f32x4*)(u1 + d0 + 4);
    f32x4 va = *(const f32x4*)(u2 + d0);
    f32x4 vb = *(const f32x4*)(u2 + d0 + 4);
    float s1 = 0.f, s2 = 0.f;
    for (int e = 0; e < 4; ++e) {
        s1 += xa[e] * ua[e] + xb[e] * ub[e];
        s2 += xa[e] * va[e] + xb[e] * vb[e];
    }
    for (int off = 32; off; off >>= 1) { s1 += __shfl_xor(s1, off); s2 += __shfl_xor(s2, off); }
    if (lane == 0) {
        float ev = s2 + scal[1];
        e_src[row] = s1 + scal[0];
        e_dst[row] = ev;
        edl[row]   = ev * L2E_;
        edl01[row] = ev * (0.01f * L2E_);
    }
}

// ---- kernel 3: M = max_j e_dst[j] ----
__global__ void max_kernel(const float* __restrict__ e_dst, float* __restrict__ scal) {
    __shared__ float red[256];
    int t = threadIdx.x;
    float m = -1e30f;
    for (int i = t; i < N_; i += 256) m = fmaxf(m, e_dst[i]);
    red[t] = m; __syncthreads();
    for (int s = 128; s; s >>= 1) { if (t < s) red[t] = fmaxf(red[t], red[t + s]); __syncthreads(); }
    if (t == 0) scal[2] = red[0];
}

// ---- kernel 4: vT[c][j] = bf16( x[j]. wv_w[c] + wv_b[c] ), MFMA ----
__global__ __launch_bounds__(256) void vt_kernel(const float* __restrict__ x,
        const float* __restrict__ wv_w, const float* __restrict__ wv_b,
        ushort* __restrict__ vT) {
    int wid = threadIdx.x >> 6, lane = threadIdx.x & 63;
    int ln16 = lane & 15, kg = lane >> 4;
    int cb = blockIdx.y * 64;                 // c block (8 blocks)
    int jb = blockIdx.x * 256 + wid * 64;     // j block (32 blocks x 4 waves)
    f32x4 acc[4][4] = {};
    for (int k0 = 0; k0 < DIM_; k0 += 32) {
        int kk = k0 + kg * 8;
        short8 afr[4], bfr[4];
        for (int mg = 0; mg < 4; ++mg) {
            const float* p = wv_w + (size_t)(cb + mg * 16 + ln16) * DIM_ + kk;
            f32x4 lo = *(const f32x4*)p, hi = *(const f32x4*)(p + 4);
            short8 f;
            for (int e = 0; e < 4; ++e) { f[e] = (short)f2bf(lo[e]); f[e + 4] = (short)f2bf(hi[e]); }
            afr[mg] = f;
        }
        for (int ng = 0; ng < 4; ++ng) {
            const float* p = x + (size_t)(jb + ng * 16 + ln16) * DIM_ + kk;
            f32x4 lo = *(const f32x4*)p, hi = *(const f32x4*)(p + 4);
            short8 f;
            for (int e = 0; e < 4; ++e) { f[e] = (short)f2bf(lo[e]); f[e + 4] = (short)f2bf(hi[e]); }
            bfr[ng] = f;
        }
        for (int mg = 0; mg < 4; ++mg)
            for (int ng = 0; ng < 4; ++ng)
                acc[mg][ng] = __builtin_amdgcn_mfma_f32_16x16x32_bf16(afr[mg], bfr[ng], acc[mg][ng], 0, 0, 0);
    }
    for (int mg = 0; mg < 4; ++mg) {
        for (int r = 0; r < 4; ++r) {
            int c_row = cb + mg * 16 + kg * 4 + r;
            float bias = wv_b[c_row];
            for (int ng = 0; ng < 4; ++ng) {
                int j_col = jb + ng * 16 + ln16;
                vT[(size_t)c_row * N_ + j_col] = f2bf(acc[mg][ng][r] + bias);
            }
        }
    }
}

// ---- kernel 5 (transposed roles): A = vT (64 c), B = generated P^T (128 i) ----
// out_partial[i][c] = sum_j p[i][j] * v[j][c] over this block's j-range
__global__ __launch_bounds__(256, 2) void attn_t_kernel(const ushort* __restrict__ vT,
        const float* __restrict__ e_src, const float* __restrict__ edl,
        const float* __restrict__ edl01, const float* __restrict__ scal,
        float* __restrict__ out, float* __restrict__ wsparts, float* __restrict__ zpart,
        int jlen) {
    int wid = threadIdx.x >> 6, lane = threadIdx.x & 63;
    int ln16 = lane & 15, kg = lane >> 4;
    int bx = blockIdx.x;
    int c0 = (bx & 7) * 64;          // c-block -> XCD affinity (bx % 8)
    int rest = bx >> 3;
    int ib = rest & 15;
    int js = rest >> 4;
    int i0 = ib * 512 + wid * 128;

    float M = scal[2];
    float A1[8], A2[8];
#pragma unroll
    for (int ng = 0; ng < 8; ++ng) {
        float es = e_src[i0 + ng * 16 + ln16];
        float sm = es + M;
        float m = fmaxf(sm, 0.01f * sm);          // analytic row max of leaky logits
        A1[ng] = (es - m) * L2E_ + CBIAS_;
        A2[ng] = (0.01f * es - m) * L2E_ + CBIAS_;
    }

    f32x4 acc[4][8] = {};
    f32x4 zc[8] = {};
    short8 onesA;
#pragma unroll
    for (int e = 0; e < 8; ++e) onesA[e] = (short)0x3F80;

    const ushort* va[4];
#pragma unroll
    for (int mg = 0; mg < 4; ++mg)
        va[mg] = vT + (size_t)(c0 + mg * 16 + ln16) * N_ + kg * 8;

    int j0 = js * jlen, j1 = j0 + jlen;
    for (int jj = j0; jj < j1; jj += 32) {
        short8 a0 = *(const short8*)(va[0] + jj);
        short8 a1 = *(const short8*)(va[1] + jj);
        short8 a2 = *(const short8*)(va[2] + jj);
        short8 a3 = *(const short8*)(va[3] + jj);
        f32x4 d0 = *(const f32x4*)(edl + jj + kg * 8);
        f32x4 d1 = *(const f32x4*)(edl + jj + kg * 8 + 4);
        f32x4 q0 = *(const f32x4*)(edl01 + jj + kg * 8);
        f32x4 q1 = *(const f32x4*)(edl01 + jj + kg * 8 + 4);
#pragma unroll
        for (int ng = 0; ng < 8; ++ng) {
            float p0 = fexp2(fmaxf(A1[ng] + d0[0], A2[ng] + q0[0]));
            float p1 = fexp2(fmaxf(A1[ng] + d0[1], A2[ng] + q0[1]));
            float p2 = fexp2(fmaxf(A1[ng] + d0[2], A2[ng] + q0[2]));
            float p3 = fexp2(fmaxf(A1[ng] + d0[3], A2[ng] + q0[3]));
            float p4 = fexp2(fmaxf(A1[ng] + d1[0], A2[ng] + q1[0]));
            float p5 = fexp2(fmaxf(A1[ng] + d1[1], A2[ng] + q1[1]));
            float p6 = fexp2(fmaxf(A1[ng] + d1[2], A2[ng] + q1[2]));
            float p7 = fexp2(fmaxf(A1[ng] + d1[3], A2[ng] + q1[3]));
            union { short8 s; unsigned u[4]; } bb;
            bb.u[0] = __builtin_amdgcn_perm(__float_as_uint(p1), __float_as_uint(p0), 0x07060302u);
            bb.u[1] = __builtin_amdgcn_perm(__float_as_uint(p3), __float_as_uint(p2), 0x07060302u);
            bb.u[2] = __builtin_amdgcn_perm(__float_as_uint(p5), __float_as_uint(p4), 0x07060302u);
            bb.u[3] = __builtin_amdgcn_perm(__float_as_uint(p7), __float_as_uint(p6), 0x07060302u);
            zc[ng]     = __builtin_amdgcn_mfma_f32_16x16x32_bf16(onesA, bb.s, zc[ng], 0, 0, 0);
            acc[0][ng] = __builtin_amdgcn_mfma_f32_16x16x32_bf16(a0,    bb.s, acc[0][ng], 0, 0, 0);
            acc[1][ng] = __builtin_amdgcn_mfma_f32_16x16x32_bf16(a1,    bb.s, acc[1][ng], 0, 0, 0);
            acc[2][ng] = __builtin_amdgcn_mfma_f32_16x16x32_bf16(a2,    bb.s, acc[2][ng], 0, 0, 0);
            acc[3][ng] = __builtin_amdgcn_mfma_f32_16x16x32_bf16(a3,    bb.s, acc[3][ng], 0, 0, 0);
        }
    }

    float* pp = (js == 0) ? out : (wsparts + (size_t)(js - 1) * ((size_t)N_ * DV_));
#pragma unroll
    for (int mg = 0; mg < 4; ++mg) {
        int c = c0 + mg * 16 + kg * 4;
#pragma unroll
        for (int ng = 0; ng < 8; ++ng) {
            int i = i0 + ng * 16 + ln16;
            *(f32x4*)(pp + (size_t)i * DV_ + c) = acc[mg][ng];
        }
    }
    if (c0 == 0 && kg == 0) {
#pragma unroll
        for (int ng = 0; ng < 8; ++ng)
            zpart[js * N_ + i0 + ng * 16 + ln16] = zc[ng][0];
    }
}

// ---- kernel 6: out = (sum of partials) / z ----
__global__ __launch_bounds__(256) void reduce_kernel(float* __restrict__ out,
        const float* __restrict__ wsparts, const float* __restrict__ zpart, int JS) {
    size_t flat4 = (size_t)blockIdx.x * 256 + threadIdx.x;   // over N*DV/4
    int i = (int)(flat4 >> 7);                               // 512/4 = 128 per row
    f32x4 s = ((f32x4*)out)[flat4];
    float z = zpart[i];
    for (int js = 1; js < JS; ++js) {
        s += ((const f32x4*)(wsparts + (size_t)(js - 1) * ((size_t)N_ * DV_)))[flat4];
        z += zpart[js * N_ + i];
    }
    float rz = 1.0f / z;
    ((f32x4*)out)[flat4] = s * rz;
}

extern "C" void kernel_launch(void* const* d_in, const int* in_sizes, int n_in,
                              void* d_out, int out_size, void* d_ws, size_t ws_size,
                              hipStream_t stream) {
    const float* x    = (const float*)d_in[0];
    const float* w_w  = (const float*)d_in[1];
    const float* w_b  = (const float*)d_in[2];
    const float* wv_w = (const float*)d_in[3];
    const float* wv_b = (const float*)d_in[4];
    const float* a    = (const float*)d_in[5];
    float* out = (float*)d_out;
    char* ws = (char*)d_ws;

    ushort* vT    = (ushort*)ws;                    // 8,388,608 B
    float*  u1    = (float*)(ws + 8388608);
    float*  u2    = (float*)(ws + 8390656);
    float*  e_src = (float*)(ws + 8392704);
    float*  e_dst = (float*)(ws + 8425472);
    float*  edl   = (float*)(ws + 8458240);
    float*  edl01 = (float*)(ws + 8491008);
    float*  scal  = (float*)(ws + 8523776);
    float*  zpart = (float*)(ws + 8523840);         // 4 * 32 KiB
    float*  wsparts = (float*)(ws + (16u << 20));   // j-split partials, 16 MB each

    size_t partBytes = (size_t)N_ * DV_ * 4;        // 16 MiB
    int JS = 1;
    if (ws_size >= (16u << 20) + 3 * partBytes)      JS = 4;
    else if (ws_size >= (16u << 20) + 1 * partBytes) JS = 2;
    int jlen = N_ / JS;

    hipLaunchKernelGGL(prep_kernel, dim3(1),      dim3(512), 0, stream, w_w, w_b, a, u1, u2, scal);
    hipLaunchKernelGGL(e_kernel,    dim3(N_ / 4), dim3(256), 0, stream, x, u1, u2, scal, e_src, e_dst, edl, edl01);
    hipLaunchKernelGGL(max_kernel,  dim3(1),      dim3(256), 0, stream, e_dst, scal);
    hipLaunchKernelGGL(vt_kernel,   dim3(32, 8),  dim3(256), 0, stream, x, wv_w, wv_b, vT);
    hipLaunchKernelGGL(attn_t_kernel, dim3(8 * 16 * JS), dim3(256), 0, stream,
                       vT, e_src, edl, edl01, scal, out, wsparts, zpart, jlen);
    hipLaunchKernelGGL(reduce_kernel, dim3(N_ * DV_ / 4 / 256), dim3(256), 0, stream,
                       out, wsparts, zpart, JS);
}